// Round 15
// baseline (150.740 us; speedup 1.0000x reference)
//
#include <hip/hip_runtime.h>

typedef unsigned int uint32;
typedef unsigned long long uint64;
typedef unsigned short ushort_t;
typedef _Float16 h2_t __attribute__((ext_vector_type(2)));
typedef float  f32x2 __attribute__((ext_vector_type(2)));
typedef float  f32x4 __attribute__((ext_vector_type(4)));
typedef uint32 u32x2 __attribute__((ext_vector_type(2)));

#define KNEI 32
#define DIM 128
#define WPB 8            // waves per block (512-thread blocks: halves WG count
                         // to test the ~115 WG/us front-end dispatch-rate limit)
#define RPW 2            // rows per wave

enum { SRC_BF16 = 0, SRC_F16 = 1, SRC_F32 = 2 };

#if __has_builtin(__builtin_amdgcn_fdot2)
#define HAVE_FDOT2 1
#else
#define HAVE_FDOT2 0
#endif

__device__ __forceinline__ float bflo(uint32 u) {
    union { uint32 u; float f; } c; c.u = u << 16; return c.f;
}
__device__ __forceinline__ float bfhi(uint32 u) {
    union { uint32 u; float f; } c; c.u = u & 0xffff0000u; return c.f;
}
__device__ __forceinline__ uint32 pack_bf16_rne(float a, float b) {
    union { float f; uint32 u; } x, y; x.f = a; y.f = b;
    uint32 ua = (x.u + 0x7fffu + ((x.u >> 16) & 1u)) >> 16;
    uint32 ub = (y.u + 0x7fffu + ((y.u >> 16) & 1u)) >> 16;
    return (ua & 0xffffu) | (ub << 16);
}
__device__ __forceinline__ uint32 pack_f16(float a, float b) {
    union { h2_t h; uint32 u; } c;
    c.h.x = (_Float16)a; c.h.y = (_Float16)b;
    return c.u;
}
__device__ __forceinline__ h2_t as_h2(uint32 u) {
    union { uint32 u; h2_t h; } c; c.u = u; return c.h;
}

// h: bf16 iff bits 14..7 of every sampled dword look like a bf16 exponent.
__device__ __forceinline__ bool probe_bf16(const void* h, int lane) {
    const uint32 hs = ((const uint32*)h)[lane];
    const uint32 e  = (hs >> 7) & 0xFFu;
    const bool  tb  = (e >= 90u) && (e <= 140u);
    return (__ballot(tb) == ~0ull);
}

// Score + softmax + weighted-sum + store for ONE row whose 32x128 tile (packed
// 16-bit) lives in ev[8] spread over all 64 lanes (lane = 16*r4 + c owns
// neighbor k = 4*it + r4, dims [8c, 8c+8)).   [R12 golden — byte-identical]
template<int SRC>
__device__ __forceinline__ void process_row(
    const uint4* ev, const float* an, const uint32* anp, float base,
    void* __restrict__ outv, size_t n, int lane, int r4, int c)
{
    constexpr bool F32 = (SRC != SRC_BF16);

    // score partials s[it] = dot(row[8c..8c+8), att_nei[8c..8c+8))
    float s[8];
    #pragma unroll
    for (int it = 0; it < 8; ++it) {
        const uint4 e = ev[it];
        if constexpr (SRC == SRC_BF16) {
            s[it] = bflo(e.x) * an[0] + bfhi(e.x) * an[1]
                  + bflo(e.y) * an[2] + bfhi(e.y) * an[3]
                  + bflo(e.z) * an[4] + bfhi(e.z) * an[5]
                  + bflo(e.w) * an[6] + bfhi(e.w) * an[7];
        } else {
#if HAVE_FDOT2
            // 4 chained v_dot2_f32_f16: packed dwords consumed directly.
            s[it] = __builtin_amdgcn_fdot2(as_h2(e.x), as_h2(anp[0]),
                    __builtin_amdgcn_fdot2(as_h2(e.y), as_h2(anp[1]),
                    __builtin_amdgcn_fdot2(as_h2(e.z), as_h2(anp[2]),
                    __builtin_amdgcn_fdot2(as_h2(e.w), as_h2(anp[3]),
                                           0.f, false), false), false), false);
#else
            const h2_t e0 = as_h2(e.x), e1 = as_h2(e.y), e2 = as_h2(e.z), e3 = as_h2(e.w);
            const float t0 = fmaf((float)e0.x, an[0],
                             fmaf((float)e0.y, an[1],
                             fmaf((float)e1.x, an[2], (float)e1.y * an[3])));
            const float t1 = fmaf((float)e2.x, an[4],
                             fmaf((float)e2.y, an[5],
                             fmaf((float)e3.x, an[6], (float)e3.y * an[7])));
            s[it] = t0 + t1;
#endif
        }
    }
    // reduce over c (bits 0..3): every lane in a 16-group gets its k's full dot
    #pragma unroll
    for (int off = 1; off <= 8; off <<= 1) {
        #pragma unroll
        for (int it = 0; it < 8; ++it)
            s[it] += __shfl_xor(s[it], off, 64);
    }
    #pragma unroll
    for (int it = 0; it < 8; ++it) {
        const float v = base + s[it];
        s[it] = (v > 0.f) ? v : 0.01f * v;     // leaky_relu
    }

    // softmax over 32 neighbors: local over it, then across r4 groups (bits 4,5)
    float m = s[0];
    #pragma unroll
    for (int it = 1; it < 8; ++it) m = fmaxf(m, s[it]);
    m = fmaxf(m, __shfl_xor(m, 16, 64));
    m = fmaxf(m, __shfl_xor(m, 32, 64));

    float w[8];
    float sum = 0.f;
    #pragma unroll
    for (int it = 0; it < 8; ++it) { w[it] = __expf(s[it] - m); sum += w[it]; }
    sum += __shfl_xor(sum, 16, 64);
    sum += __shfl_xor(sum, 32, 64);
    const float inv = 1.0f / sum;

    // weighted accumulation (weights already on the owning lane)
    float acc[8] = {0.f, 0.f, 0.f, 0.f, 0.f, 0.f, 0.f, 0.f};
    #pragma unroll
    for (int it = 0; it < 8; ++it) {
        const float wk = w[it] * inv;
        const uint4 e = ev[it];
        if constexpr (SRC == SRC_BF16) {
            acc[0] = fmaf(wk, bflo(e.x), acc[0]);
            acc[1] = fmaf(wk, bfhi(e.x), acc[1]);
            acc[2] = fmaf(wk, bflo(e.y), acc[2]);
            acc[3] = fmaf(wk, bfhi(e.y), acc[3]);
            acc[4] = fmaf(wk, bflo(e.z), acc[4]);
            acc[5] = fmaf(wk, bfhi(e.z), acc[5]);
            acc[6] = fmaf(wk, bflo(e.w), acc[6]);
            acc[7] = fmaf(wk, bfhi(e.w), acc[7]);
        } else {
            const h2_t e0 = as_h2(e.x), e1 = as_h2(e.y), e2 = as_h2(e.z), e3 = as_h2(e.w);
            acc[0] = fmaf(wk, (float)e0.x, acc[0]);
            acc[1] = fmaf(wk, (float)e0.y, acc[1]);
            acc[2] = fmaf(wk, (float)e1.x, acc[2]);
            acc[3] = fmaf(wk, (float)e1.y, acc[3]);
            acc[4] = fmaf(wk, (float)e2.x, acc[4]);
            acc[5] = fmaf(wk, (float)e2.y, acc[5]);
            acc[6] = fmaf(wk, (float)e3.x, acc[6]);
            acc[7] = fmaf(wk, (float)e3.y, acc[7]);
        }
    }
    #pragma unroll
    for (int d = 0; d < 8; ++d) acc[d] += __shfl_xor(acc[d], 16, 64);
    #pragma unroll
    for (int d = 0; d < 8; ++d) acc[d] += __shfl_xor(acc[d], 32, 64);

    // lane stores dims [8c + 2*r4, +2): fully coalesced; NT (never re-read)
    const float q0a = (r4 & 2) ? acc[4] : acc[0];
    const float q0b = (r4 & 2) ? acc[5] : acc[1];
    const float q1a = (r4 & 2) ? acc[6] : acc[2];
    const float q1b = (r4 & 2) ? acc[7] : acc[3];
    const float o0 = (r4 & 1) ? q1a : q0a;
    const float o1 = (r4 & 1) ? q1b : q0b;

    if (F32) {
        f32x2 o; o.x = o0; o.y = o1;
        __builtin_nontemporal_store(o, (f32x2*)((float*)outv + n * DIM) + c * 4 + r4);
    } else {
        __builtin_nontemporal_store(pack_bf16_rne(o0, o1),
            (uint32*)((ushort_t*)outv + n * DIM) + c * 4 + r4);
    }
}

// Two rows per wave: shared nei load (one coalesced 64-lane load covers both
// rows), shared att/an loads, 16 gather loads issued up front.   [R12 golden]
template<int SRC>
__device__ __forceinline__ void run_two(
    const void* __restrict__ hsv, const void* __restrict__ hrv,
    const void* __restrict__ attv, void* __restrict__ outv,
    const void* __restrict__ neiv, bool i64, int Mrows,
    int n0, bool valid2, int lane)
{
    constexpr bool F32 = (SRC != SRC_BF16);
    const int r4 = lane >> 4;
    const int c  = lane & 15;

    // nei indices: lanes 0..31 -> row n0, lanes 32..63 -> row n0+1 (contiguous)
    const size_t ebase = (size_t)n0 * KNEI;
    const int esel = valid2 ? lane : (lane & 31);   // clamp if row B absent
    int idxv;
    if (i64) idxv = (int)__builtin_nontemporal_load((const long long*)neiv + ebase + esel);
    else     idxv = __builtin_nontemporal_load((const int*)neiv + ebase + esel);
    idxv = min(max(idxv, 0), Mrows - 1);            // OOB armor

    int rows_a[8], rows_b[8];
    #pragma unroll
    for (int it = 0; it < 8; ++it) {
        rows_a[it] = __shfl(idxv, it * 4 + r4, 64);
        rows_b[it] = __shfl(idxv, 32 + it * 4 + r4, 64);
    }

    // issue ALL 16 gather loads before any compute
    uint4 eva[8], evb[8];
    #pragma unroll
    for (int it = 0; it < 8; ++it) {
        if constexpr (SRC == SRC_F32) {
            const float4* sp = (const float4*)hsv + ((size_t)rows_a[it] << 5) + c * 2;
            const float4 p0 = sp[0], p1 = sp[1];
            eva[it].x = pack_f16(p0.x, p0.y);
            eva[it].y = pack_f16(p0.z, p0.w);
            eva[it].z = pack_f16(p1.x, p1.y);
            eva[it].w = pack_f16(p1.z, p1.w);
        } else {
            eva[it] = *((const uint4*)hsv + ((size_t)rows_a[it] << 4) + c);
        }
    }
    #pragma unroll
    for (int it = 0; it < 8; ++it) {
        if constexpr (SRC == SRC_F32) {
            const float4* sp = (const float4*)hsv + ((size_t)rows_b[it] << 5) + c * 2;
            const float4 p0 = sp[0], p1 = sp[1];
            evb[it].x = pack_f16(p0.x, p0.y);
            evb[it].y = pack_f16(p0.z, p0.w);
            evb[it].z = pack_f16(p1.x, p1.y);
            evb[it].w = pack_f16(p1.z, p1.w);
        } else {
            evb[it] = *((const uint4*)hsv + ((size_t)rows_b[it] << 4) + c);
        }
    }

    // base scores for BOTH rows in one pass: half-wave r2 handles row n0+r2,
    // lane covers dims [4*l5, 4*l5+4).
    const int r2 = lane >> 5;
    const int l5 = lane & 31;
    const size_t brow = (size_t)n0 + (valid2 ? r2 : 0);
    float bsum;
    if (F32) {
        const f32x4 hp = __builtin_nontemporal_load(
            (const f32x4*)((const float*)hrv + brow * DIM) + l5);
        const f32x4 ap = *((const f32x4*)attv + l5);
        bsum = hp.x * ap.x + hp.y * ap.y + hp.z * ap.z + hp.w * ap.w;
    } else {
        const u32x2 hu = __builtin_nontemporal_load(
            (const u32x2*)((const ushort_t*)hrv + brow * DIM) + l5);
        const u32x2 au = *((const u32x2*)attv + l5);
        bsum = bflo(hu.x) * bflo(au.x) + bfhi(hu.x) * bfhi(au.x)
             + bflo(hu.y) * bflo(au.y) + bfhi(hu.y) * bfhi(au.y);
    }
    #pragma unroll
    for (int off = 1; off <= 16; off <<= 1)
        bsum += __shfl_xor(bsum, off, 64);
    const float baseA = __shfl(bsum, 0, 64);
    const float baseB = __shfl(bsum, 32, 64);

    // att_nei chunk for dims [8c, 8c+8) — shared by both rows
    float an[8];
    if (F32) {
        const float4* ap = (const float4*)((const float*)attv + DIM + c * 8);
        const float4 p0 = ap[0], p1 = ap[1];
        an[0] = p0.x; an[1] = p0.y; an[2] = p0.z; an[3] = p0.w;
        an[4] = p1.x; an[5] = p1.y; an[6] = p1.z; an[7] = p1.w;
    } else {
        const uint4 au = *((const uint4*)((const ushort_t*)attv + DIM) + c);
        an[0] = bflo(au.x); an[1] = bfhi(au.x); an[2] = bflo(au.y); an[3] = bfhi(au.y);
        an[4] = bflo(au.z); an[5] = bfhi(au.z); an[6] = bflo(au.w); an[7] = bfhi(au.w);
    }

    // packed f16 att_nei pairs for the dot2 score phase (SRC_F16 only; DCE'd otherwise)
    uint32 anp[4];
    #pragma unroll
    for (int j = 0; j < 4; ++j)
        anp[j] = pack_f16(an[2 * j], an[2 * j + 1]);

    process_row<SRC>(eva, an, anp, baseA, outv, (size_t)n0, lane, r4, c);
    if (valid2)
        process_row<SRC>(evb, an, anp, baseB, outv, (size_t)n0 + 1, lane, r4, c);
}

__global__ __launch_bounds__(64 * WPB) void gat_kernel(
    const void* __restrict__ nei, const void* __restrict__ h,
    const void* __restrict__ h_refer, const void* __restrict__ att,
    void* __restrict__ out, const void* __restrict__ hf16,
    int N, int Mrows, int use_ws)
{
    const int tid  = threadIdx.x;
    const int lane = tid & 63;
    const int n0   = (blockIdx.x * WPB + (tid >> 6)) * RPW;

    // dtype probes (wave-uniform)
    const bool is_bf16 = probe_bf16(h, lane);
    const uint32 nhi = ((const uint32*)nei)[2 * lane + 1];
    const bool  i64  = (__ballot(nhi == 0u) == ~0ull);

    if (n0 >= N) return;   // whole wave exits together; no barriers anywhere
    const bool valid2 = (n0 + 1 < N);

    if (is_bf16)     run_two<SRC_BF16>(h,    h_refer, att, out, nei, i64, Mrows, n0, valid2, lane);
    else if (use_ws) run_two<SRC_F16 >(hf16, h_refer, att, out, nei, i64, Mrows, n0, valid2, lane);
    else             run_two<SRC_F32 >(h,    h_refer, att, out, nei, i64, Mrows, n0, valid2, lane);
}

// h (f32) -> fp16 rows in workspace. Early-out if h is already bf16.
__global__ __launch_bounds__(256) void conv_kernel(
    const void* __restrict__ h, uint4* __restrict__ ws, long long ngroups)
{
    if (probe_bf16(h, threadIdx.x & 63)) return;
    const long long i = (long long)blockIdx.x * 256 + threadIdx.x;
    if (i >= ngroups) return;
    const f32x4* sp = (const f32x4*)h + i * 2;
    const f32x4 p0 = __builtin_nontemporal_load(sp);
    const f32x4 p1 = __builtin_nontemporal_load(sp + 1);
    uint4 o;
    o.x = pack_f16(p0.x, p0.y);
    o.y = pack_f16(p0.z, p0.w);
    o.z = pack_f16(p1.x, p1.y);
    o.w = pack_f16(p1.z, p1.w);
    ws[i] = o;
}

extern "C" void kernel_launch(void* const* d_in, const int* in_sizes, int n_in,
                              void* d_out, int out_size, void* d_ws, size_t ws_size,
                              hipStream_t stream) {
    const int N = out_size / DIM;          // authoritative: output rows
    const int M = in_sizes[1] / DIM;       // h rows (element count is dtype-independent)

    const size_t need = (size_t)M * DIM * sizeof(ushort_t);
    const int use_ws = (d_ws != nullptr && ws_size >= need) ? 1 : 0;

    if (use_ws) {
        const long long ngroups = (long long)M * (DIM / 8);   // 8 elems per thread
        dim3 cg((unsigned)((ngroups + 255) / 256)), cb(256);
        conv_kernel<<<cg, cb, 0, stream>>>(d_in[1], (uint4*)d_ws, ngroups);
    }

    const int rows_per_block = WPB * RPW;
    dim3 grid((N + rows_per_block - 1) / rows_per_block), block(64 * WPB);
    gat_kernel<<<grid, block, 0, stream>>>(d_in[0], d_in[1], d_in[2], d_in[3],
                                           d_out, d_ws, N, M, use_ws);
}

// Round 16
// 146.916 us; speedup vs baseline: 1.0260x; 1.0260x over previous
//
#include <hip/hip_runtime.h>

typedef unsigned int uint32;
typedef unsigned long long uint64;
typedef unsigned short ushort_t;
typedef _Float16 h2_t __attribute__((ext_vector_type(2)));
typedef float  f32x2 __attribute__((ext_vector_type(2)));
typedef float  f32x4 __attribute__((ext_vector_type(4)));
typedef uint32 u32x2 __attribute__((ext_vector_type(2)));

#define KNEI 32
#define DIM 128
#define WPB 4            // waves per block (R15: WPB=8 regressed ~7%)
#define RPW 2            // rows per wave

enum { SRC_BF16 = 0, SRC_F16 = 1, SRC_F32 = 2 };

#if __has_builtin(__builtin_amdgcn_fdot2)
#define HAVE_FDOT2 1
#else
#define HAVE_FDOT2 0
#endif

__device__ __forceinline__ float bflo(uint32 u) {
    union { uint32 u; float f; } c; c.u = u << 16; return c.f;
}
__device__ __forceinline__ float bfhi(uint32 u) {
    union { uint32 u; float f; } c; c.u = u & 0xffff0000u; return c.f;
}
__device__ __forceinline__ uint32 pack_bf16_rne(float a, float b) {
    union { float f; uint32 u; } x, y; x.f = a; y.f = b;
    uint32 ua = (x.u + 0x7fffu + ((x.u >> 16) & 1u)) >> 16;
    uint32 ub = (y.u + 0x7fffu + ((y.u >> 16) & 1u)) >> 16;
    return (ua & 0xffffu) | (ub << 16);
}
__device__ __forceinline__ uint32 pack_f16(float a, float b) {
    union { h2_t h; uint32 u; } c;
    c.h.x = (_Float16)a; c.h.y = (_Float16)b;
    return c.u;
}
__device__ __forceinline__ h2_t as_h2(uint32 u) {
    union { uint32 u; h2_t h; } c; c.u = u; return c.h;
}

// h: bf16 iff bits 14..7 of every sampled dword look like a bf16 exponent.
__device__ __forceinline__ bool probe_bf16(const void* h, int lane) {
    const uint32 hs = ((const uint32*)h)[lane];
    const uint32 e  = (hs >> 7) & 0xFFu;
    const bool  tb  = (e >= 90u) && (e <= 140u);
    return (__ballot(tb) == ~0ull);
}

// Score + softmax + weighted-sum + store for ONE row whose 32x128 tile (packed
// 16-bit) lives in ev[8] spread over all 64 lanes (lane = 16*r4 + c owns
// neighbor k = 4*it + r4, dims [8c, 8c+8)).
// [R12 GOLDEN — session optimum, reproduced 2x (R12: 54.0, R14: 53.7-54.6 us).
//  Constraint (R5-R10, R13): any change pushing VGPR past the 64-granule
//  halves the wave-slot cap, costing ~25% — more than any ILP gain funds.
//  R15: occupancy ~1/3-of-cap is gather-latency backpressure, not dispatch.]
template<int SRC>
__device__ __forceinline__ void process_row(
    const uint4* ev, const float* an, const uint32* anp, float base,
    void* __restrict__ outv, size_t n, int lane, int r4, int c)
{
    constexpr bool F32 = (SRC != SRC_BF16);

    // score partials s[it] = dot(row[8c..8c+8), att_nei[8c..8c+8))
    float s[8];
    #pragma unroll
    for (int it = 0; it < 8; ++it) {
        const uint4 e = ev[it];
        if constexpr (SRC == SRC_BF16) {
            s[it] = bflo(e.x) * an[0] + bfhi(e.x) * an[1]
                  + bflo(e.y) * an[2] + bfhi(e.y) * an[3]
                  + bflo(e.z) * an[4] + bfhi(e.z) * an[5]
                  + bflo(e.w) * an[6] + bfhi(e.w) * an[7];
        } else {
#if HAVE_FDOT2
            // 4 chained v_dot2_f32_f16: packed dwords consumed directly.
            s[it] = __builtin_amdgcn_fdot2(as_h2(e.x), as_h2(anp[0]),
                    __builtin_amdgcn_fdot2(as_h2(e.y), as_h2(anp[1]),
                    __builtin_amdgcn_fdot2(as_h2(e.z), as_h2(anp[2]),
                    __builtin_amdgcn_fdot2(as_h2(e.w), as_h2(anp[3]),
                                           0.f, false), false), false), false);
#else
            const h2_t e0 = as_h2(e.x), e1 = as_h2(e.y), e2 = as_h2(e.z), e3 = as_h2(e.w);
            const float t0 = fmaf((float)e0.x, an[0],
                             fmaf((float)e0.y, an[1],
                             fmaf((float)e1.x, an[2], (float)e1.y * an[3])));
            const float t1 = fmaf((float)e2.x, an[4],
                             fmaf((float)e2.y, an[5],
                             fmaf((float)e3.x, an[6], (float)e3.y * an[7])));
            s[it] = t0 + t1;
#endif
        }
    }
    // reduce over c (bits 0..3): every lane in a 16-group gets its k's full dot
    #pragma unroll
    for (int off = 1; off <= 8; off <<= 1) {
        #pragma unroll
        for (int it = 0; it < 8; ++it)
            s[it] += __shfl_xor(s[it], off, 64);
    }
    #pragma unroll
    for (int it = 0; it < 8; ++it) {
        const float v = base + s[it];
        s[it] = (v > 0.f) ? v : 0.01f * v;     // leaky_relu
    }

    // softmax over 32 neighbors: local over it, then across r4 groups (bits 4,5)
    float m = s[0];
    #pragma unroll
    for (int it = 1; it < 8; ++it) m = fmaxf(m, s[it]);
    m = fmaxf(m, __shfl_xor(m, 16, 64));
    m = fmaxf(m, __shfl_xor(m, 32, 64));

    float w[8];
    float sum = 0.f;
    #pragma unroll
    for (int it = 0; it < 8; ++it) { w[it] = __expf(s[it] - m); sum += w[it]; }
    sum += __shfl_xor(sum, 16, 64);
    sum += __shfl_xor(sum, 32, 64);
    const float inv = 1.0f / sum;

    // weighted accumulation (weights already on the owning lane)
    float acc[8] = {0.f, 0.f, 0.f, 0.f, 0.f, 0.f, 0.f, 0.f};
    #pragma unroll
    for (int it = 0; it < 8; ++it) {
        const float wk = w[it] * inv;
        const uint4 e = ev[it];
        if constexpr (SRC == SRC_BF16) {
            acc[0] = fmaf(wk, bflo(e.x), acc[0]);
            acc[1] = fmaf(wk, bfhi(e.x), acc[1]);
            acc[2] = fmaf(wk, bflo(e.y), acc[2]);
            acc[3] = fmaf(wk, bfhi(e.y), acc[3]);
            acc[4] = fmaf(wk, bflo(e.z), acc[4]);
            acc[5] = fmaf(wk, bfhi(e.z), acc[5]);
            acc[6] = fmaf(wk, bflo(e.w), acc[6]);
            acc[7] = fmaf(wk, bfhi(e.w), acc[7]);
        } else {
            const h2_t e0 = as_h2(e.x), e1 = as_h2(e.y), e2 = as_h2(e.z), e3 = as_h2(e.w);
            acc[0] = fmaf(wk, (float)e0.x, acc[0]);
            acc[1] = fmaf(wk, (float)e0.y, acc[1]);
            acc[2] = fmaf(wk, (float)e1.x, acc[2]);
            acc[3] = fmaf(wk, (float)e1.y, acc[3]);
            acc[4] = fmaf(wk, (float)e2.x, acc[4]);
            acc[5] = fmaf(wk, (float)e2.y, acc[5]);
            acc[6] = fmaf(wk, (float)e3.x, acc[6]);
            acc[7] = fmaf(wk, (float)e3.y, acc[7]);
        }
    }
    #pragma unroll
    for (int d = 0; d < 8; ++d) acc[d] += __shfl_xor(acc[d], 16, 64);
    #pragma unroll
    for (int d = 0; d < 8; ++d) acc[d] += __shfl_xor(acc[d], 32, 64);

    // lane stores dims [8c + 2*r4, +2): fully coalesced; NT (never re-read)
    const float q0a = (r4 & 2) ? acc[4] : acc[0];
    const float q0b = (r4 & 2) ? acc[5] : acc[1];
    const float q1a = (r4 & 2) ? acc[6] : acc[2];
    const float q1b = (r4 & 2) ? acc[7] : acc[3];
    const float o0 = (r4 & 1) ? q1a : q0a;
    const float o1 = (r4 & 1) ? q1b : q0b;

    if (F32) {
        f32x2 o; o.x = o0; o.y = o1;
        __builtin_nontemporal_store(o, (f32x2*)((float*)outv + n * DIM) + c * 4 + r4);
    } else {
        __builtin_nontemporal_store(pack_bf16_rne(o0, o1),
            (uint32*)((ushort_t*)outv + n * DIM) + c * 4 + r4);
    }
}

// Two rows per wave: shared nei load (one coalesced 64-lane load covers both
// rows), shared att/an loads, 16 gather loads issued up front.   [R12 golden]
template<int SRC>
__device__ __forceinline__ void run_two(
    const void* __restrict__ hsv, const void* __restrict__ hrv,
    const void* __restrict__ attv, void* __restrict__ outv,
    const void* __restrict__ neiv, bool i64, int Mrows,
    int n0, bool valid2, int lane)
{
    constexpr bool F32 = (SRC != SRC_BF16);
    const int r4 = lane >> 4;
    const int c  = lane & 15;

    // nei indices: lanes 0..31 -> row n0, lanes 32..63 -> row n0+1 (contiguous)
    const size_t ebase = (size_t)n0 * KNEI;
    const int esel = valid2 ? lane : (lane & 31);   // clamp if row B absent
    int idxv;
    if (i64) idxv = (int)__builtin_nontemporal_load((const long long*)neiv + ebase + esel);
    else     idxv = __builtin_nontemporal_load((const int*)neiv + ebase + esel);
    idxv = min(max(idxv, 0), Mrows - 1);            // OOB armor

    int rows_a[8], rows_b[8];
    #pragma unroll
    for (int it = 0; it < 8; ++it) {
        rows_a[it] = __shfl(idxv, it * 4 + r4, 64);
        rows_b[it] = __shfl(idxv, 32 + it * 4 + r4, 64);
    }

    // issue ALL 16 gather loads before any compute
    uint4 eva[8], evb[8];
    #pragma unroll
    for (int it = 0; it < 8; ++it) {
        if constexpr (SRC == SRC_F32) {
            const float4* sp = (const float4*)hsv + ((size_t)rows_a[it] << 5) + c * 2;
            const float4 p0 = sp[0], p1 = sp[1];
            eva[it].x = pack_f16(p0.x, p0.y);
            eva[it].y = pack_f16(p0.z, p0.w);
            eva[it].z = pack_f16(p1.x, p1.y);
            eva[it].w = pack_f16(p1.z, p1.w);
        } else {
            eva[it] = *((const uint4*)hsv + ((size_t)rows_a[it] << 4) + c);
        }
    }
    #pragma unroll
    for (int it = 0; it < 8; ++it) {
        if constexpr (SRC == SRC_F32) {
            const float4* sp = (const float4*)hsv + ((size_t)rows_b[it] << 5) + c * 2;
            const float4 p0 = sp[0], p1 = sp[1];
            evb[it].x = pack_f16(p0.x, p0.y);
            evb[it].y = pack_f16(p0.z, p0.w);
            evb[it].z = pack_f16(p1.x, p1.y);
            evb[it].w = pack_f16(p1.z, p1.w);
        } else {
            evb[it] = *((const uint4*)hsv + ((size_t)rows_b[it] << 4) + c);
        }
    }

    // base scores for BOTH rows in one pass: half-wave r2 handles row n0+r2,
    // lane covers dims [4*l5, 4*l5+4).
    const int r2 = lane >> 5;
    const int l5 = lane & 31;
    const size_t brow = (size_t)n0 + (valid2 ? r2 : 0);
    float bsum;
    if (F32) {
        const f32x4 hp = __builtin_nontemporal_load(
            (const f32x4*)((const float*)hrv + brow * DIM) + l5);
        const f32x4 ap = *((const f32x4*)attv + l5);
        bsum = hp.x * ap.x + hp.y * ap.y + hp.z * ap.z + hp.w * ap.w;
    } else {
        const u32x2 hu = __builtin_nontemporal_load(
            (const u32x2*)((const ushort_t*)hrv + brow * DIM) + l5);
        const u32x2 au = *((const u32x2*)attv + l5);
        bsum = bflo(hu.x) * bflo(au.x) + bfhi(hu.x) * bfhi(au.x)
             + bflo(hu.y) * bflo(au.y) + bfhi(hu.y) * bfhi(au.y);
    }
    #pragma unroll
    for (int off = 1; off <= 16; off <<= 1)
        bsum += __shfl_xor(bsum, off, 64);
    const float baseA = __shfl(bsum, 0, 64);
    const float baseB = __shfl(bsum, 32, 64);

    // att_nei chunk for dims [8c, 8c+8) — shared by both rows
    float an[8];
    if (F32) {
        const float4* ap = (const float4*)((const float*)attv + DIM + c * 8);
        const float4 p0 = ap[0], p1 = ap[1];
        an[0] = p0.x; an[1] = p0.y; an[2] = p0.z; an[3] = p0.w;
        an[4] = p1.x; an[5] = p1.y; an[6] = p1.z; an[7] = p1.w;
    } else {
        const uint4 au = *((const uint4*)((const ushort_t*)attv + DIM) + c);
        an[0] = bflo(au.x); an[1] = bfhi(au.x); an[2] = bflo(au.y); an[3] = bfhi(au.y);
        an[4] = bflo(au.z); an[5] = bfhi(au.z); an[6] = bflo(au.w); an[7] = bfhi(au.w);
    }

    // packed f16 att_nei pairs for the dot2 score phase (SRC_F16 only; DCE'd otherwise)
    uint32 anp[4];
    #pragma unroll
    for (int j = 0; j < 4; ++j)
        anp[j] = pack_f16(an[2 * j], an[2 * j + 1]);

    process_row<SRC>(eva, an, anp, baseA, outv, (size_t)n0, lane, r4, c);
    if (valid2)
        process_row<SRC>(evb, an, anp, baseB, outv, (size_t)n0 + 1, lane, r4, c);
}

__global__ __launch_bounds__(256) void gat_kernel(
    const void* __restrict__ nei, const void* __restrict__ h,
    const void* __restrict__ h_refer, const void* __restrict__ att,
    void* __restrict__ out, const void* __restrict__ hf16,
    int N, int Mrows, int use_ws)
{
    const int tid  = threadIdx.x;
    const int lane = tid & 63;
    const int n0   = (blockIdx.x * WPB + (tid >> 6)) * RPW;

    // dtype probes (wave-uniform)
    const bool is_bf16 = probe_bf16(h, lane);
    const uint32 nhi = ((const uint32*)nei)[2 * lane + 1];
    const bool  i64  = (__ballot(nhi == 0u) == ~0ull);

    if (n0 >= N) return;   // whole wave exits together; no barriers anywhere
    const bool valid2 = (n0 + 1 < N);

    if (is_bf16)     run_two<SRC_BF16>(h,    h_refer, att, out, nei, i64, Mrows, n0, valid2, lane);
    else if (use_ws) run_two<SRC_F16 >(hf16, h_refer, att, out, nei, i64, Mrows, n0, valid2, lane);
    else             run_two<SRC_F32 >(h,    h_refer, att, out, nei, i64, Mrows, n0, valid2, lane);
}

// h (f32) -> fp16 rows in workspace. Early-out if h is already bf16.
__global__ __launch_bounds__(256) void conv_kernel(
    const void* __restrict__ h, uint4* __restrict__ ws, long long ngroups)
{
    if (probe_bf16(h, threadIdx.x & 63)) return;
    const long long i = (long long)blockIdx.x * 256 + threadIdx.x;
    if (i >= ngroups) return;
    const f32x4* sp = (const f32x4*)h + i * 2;
    const f32x4 p0 = __builtin_nontemporal_load(sp);
    const f32x4 p1 = __builtin_nontemporal_load(sp + 1);
    uint4 o;
    o.x = pack_f16(p0.x, p0.y);
    o.y = pack_f16(p0.z, p0.w);
    o.z = pack_f16(p1.x, p1.y);
    o.w = pack_f16(p1.z, p1.w);
    ws[i] = o;
}

extern "C" void kernel_launch(void* const* d_in, const int* in_sizes, int n_in,
                              void* d_out, int out_size, void* d_ws, size_t ws_size,
                              hipStream_t stream) {
    const int N = out_size / DIM;          // authoritative: output rows
    const int M = in_sizes[1] / DIM;       // h rows (element count is dtype-independent)

    const size_t need = (size_t)M * DIM * sizeof(ushort_t);
    const int use_ws = (d_ws != nullptr && ws_size >= need) ? 1 : 0;

    if (use_ws) {
        const long long ngroups = (long long)M * (DIM / 8);   // 8 elems per thread
        dim3 cg((unsigned)((ngroups + 255) / 256)), cb(256);
        conv_kernel<<<cg, cb, 0, stream>>>(d_in[1], (uint4*)d_ws, ngroups);
    }

    const int rows_per_block = WPB * RPW;
    dim3 grid((N + rows_per_block - 1) / rows_per_block), block(64 * WPB);
    gat_kernel<<<grid, block, 0, stream>>>(d_in[0], d_in[1], d_in[2], d_in[3],
                                           d_out, d_ws, N, M, use_ws);
}